// Round 1
// baseline (130.786 us; speedup 1.0000x reference)
//
#include <hip/hip_runtime.h>
#include <float.h>

#define NCNT 33   // count classes 0..32
#define NPTS 32   // max poles/zeros

// ---------- DPP helpers ----------
template<int CTRL, bool BC>
__device__ __forceinline__ int dpp_i(int old, int v) {
    return __builtin_amdgcn_update_dpp(old, v, CTRL, 0xF, 0xF, BC);
}

// full-wave (64) sum; result broadcast to all lanes via readlane 63
__device__ __forceinline__ float wave_sum63(float v) {
    v += __int_as_float(dpp_i<0x111, true>(0, __float_as_int(v))); // row_shr:1
    v += __int_as_float(dpp_i<0x112, true>(0, __float_as_int(v))); // row_shr:2
    v += __int_as_float(dpp_i<0x114, true>(0, __float_as_int(v))); // row_shr:4
    v += __int_as_float(dpp_i<0x118, true>(0, __float_as_int(v))); // row_shr:8
    v += __int_as_float(dpp_i<0x142, true>(0, __float_as_int(v))); // row_bcast:15
    v += __int_as_float(dpp_i<0x143, true>(0, __float_as_int(v))); // row_bcast:31
    return __int_as_float(__builtin_amdgcn_readlane(__float_as_int(v), 63));
}

// full-wave max; result broadcast (uniform). bound_ctrl=false + old=v so
// out-of-range source lanes contribute fmax(v,v)=v.
__device__ __forceinline__ float wave_max63(float v) {
#define MX_STEP(C)                                                                    \
    {                                                                                 \
        int o = dpp_i<C, false>(__float_as_int(v), __float_as_int(v));                \
        v = fmaxf(v, __int_as_float(o));                                              \
    }
    MX_STEP(0x111) MX_STEP(0x112) MX_STEP(0x114) MX_STEP(0x118) MX_STEP(0x142) MX_STEP(0x143)
#undef MX_STEP
    return __int_as_float(__builtin_amdgcn_readlane(__float_as_int(v), 63));
}

// rotate right by 1 within each 16-lane row (full cycle, no invalid sources)
__device__ __forceinline__ float rot_ror1(float v) {
    return __int_as_float(dpp_i<0x121, false>(__float_as_int(v), __float_as_int(v)));
}

// xor-16 lane swap within each 32-lane half (BitMode: xor=0x10, and=0x1F)
__device__ __forceinline__ float swz_x16(float v) {
    return __int_as_float(__builtin_amdgcn_ds_swizzle(__float_as_int(v), 0x401F));
}

// ---------- main kernel: 4 independent single-wave units per 256-thread block ----------
// No LDS staging: the "other side" (u,v,s) triples are exchanged wave-internally via
// shfl_xor(32) + DPP row_ror:1 rotation + ds_swizzle xor-16. u=-2x, v=-2y, s=|pt|^2
// (1e30 sentinel if invalid). Eval order fmaf(Px,u,fmaf(Py,v,s)) kept identical to the
// previous LDS version, so results are bitwise unchanged.
__global__ __launch_bounds__(256) void vltf_kernel(
    const float* __restrict__ pole_logits, const float* __restrict__ zero_logits,
    const float* __restrict__ poles_all,   const float* __restrict__ zeros_all,
    const float* __restrict__ tpoles,      const float* __restrict__ tzeros,
    const int* __restrict__ tnum_p,        const int* __restrict__ tnum_z,
    float* __restrict__ partials, int units)
{
    const int lane = threadIdx.x & 63;
    const int unit = (blockIdx.x << 2) | (threadIdx.x >> 6);
    if (unit >= units) return;
    const int row  = unit >> 1;
    const int part = unit & 1;

    const float* logits = part ? zero_logits : pole_logits;
    const float* predp  = part ? zeros_all   : poles_all;
    const float* tgtp   = part ? tzeros      : tpoles;
    const int*   tnum   = part ? tnum_z      : tnum_p;

    // ---- cross-entropy + argmax over 33 logits (lanes 0..32 active) ----
    float x = (lane < NCNT) ? logits[row * NCNT + lane] : -FLT_MAX;
    float vmax = wave_max63(x);
    unsigned long long bm = __ballot(lane < NCNT && x == vmax);
    const int np = (int)__builtin_ctzll(bm);      // first-max index == pred count (uniform)
    float e = (lane < NCNT) ? __expf(x - vmax) : 0.f;
    float sume = wave_sum63(e);
    const int nt = tnum[row];                     // target count (uniform)
    float xt = __int_as_float(__builtin_amdgcn_readlane(__float_as_int(x), nt));
    float nll = vmax + __logf(sume) - xt;

    // ---- own point; build (u,v,s) triple in registers ----
    const bool isPred = lane < 32;
    const int  idx    = lane & 31;
    const float2* ownArr = (const float2*)(isPred ? predp : tgtp);
    const float2  Pt     = ownArr[row * NPTS + idx];
    const int  nown = isPred ? np : nt;
    const bool vown = idx < nown;
    const float sreal = fmaf(Pt.x, Pt.x, Pt.y * Pt.y);

    float su = vown ? -2.f * Pt.x : 0.f;
    float sv = vown ? -2.f * Pt.y : 0.f;
    float ss = vown ? sreal       : 1e30f;

    // swap halves: pred lanes get tgt triples (same idx), tgt lanes get pred triples
    float ou = __shfl_xor(su, 32);
    float ov = __shfl_xor(sv, 32);
    float os = __shfl_xor(ss, 32);

    // ---- chamfer: min over the other side's 32 points, all in registers ----
    float m0 = FLT_MAX, m1 = FLT_MAX;
#pragma unroll
    for (int t = 0; t < 16; ++t) {
        float val = fmaf(Pt.x, ou, fmaf(Pt.y, ov, os));
        if (t & 1) m1 = fminf(m1, val); else m0 = fminf(m0, val);
        if (t < 15) { ou = rot_ror1(ou); ov = rot_ror1(ov); os = rot_ror1(os); }
    }
    // swap the two 16-lane rows within each half; then cover the other 16 points
    ou = swz_x16(ou); ov = swz_x16(ov); os = swz_x16(os);
#pragma unroll
    for (int t = 0; t < 16; ++t) {
        float val = fmaf(Pt.x, ou, fmaf(Pt.y, ov, os));
        if (t & 1) m1 = fminf(m1, val); else m0 = fminf(m0, val);
        if (t < 15) { ou = rot_ror1(ou); ov = rot_ror1(ov); os = rot_ror1(os); }
    }
    float m = fminf(m0, m1);

    // ---- per-lane term with wave-uniform special cases ----
    float T;
    if (np > 0 && nt > 0) {
        float inv_n = __builtin_amdgcn_rcpf((float)nown);
        T = vown ? (m + sreal) * inv_n : 0.f;     // |p|^2 folded in once
    } else if (np == 0 && nt == 0) {
        T = 0.f;
    } else if (np == 0) {                          // out = sum_tgt_sq
        T = (!isPred && vown) ? sreal : 0.f;
    } else {                                       // nt == 0 -> sum_pred_sq
        T = (isPred && vown) ? sreal : 0.f;
    }
    float cham = wave_sum63(T);

    if (lane == 0) partials[unit] = 5.f * nll + cham;
}

// ---------- finalize: sum 65536 partials (as 16384 float4), divide by B ----------
__global__ __launch_bounds__(1024) void vltf_finalize(
    const float4* __restrict__ p4, int n4, float invB, float* __restrict__ out)
{
    float s = 0.f;
    for (int i = threadIdx.x; i < n4; i += 1024) {
        float4 v = p4[i];
        s += (v.x + v.y) + (v.z + v.w);
    }
    s = wave_sum63(s);
    __shared__ float sh[16];
    if ((threadIdx.x & 63) == 0) sh[threadIdx.x >> 6] = s;
    __syncthreads();
    if (threadIdx.x == 0) {
        float t = 0.f;
#pragma unroll
        for (int i = 0; i < 16; ++i) t += sh[i];
        out[0] = t * invB;
    }
}

extern "C" void kernel_launch(void* const* d_in, const int* in_sizes, int n_in,
                              void* d_out, int out_size, void* d_ws, size_t ws_size,
                              hipStream_t stream) {
    const float* pole_logits = (const float*)d_in[0];
    const float* zero_logits = (const float*)d_in[1];
    const float* poles_all   = (const float*)d_in[2];
    const float* zeros_all   = (const float*)d_in[3];
    const float* tpoles      = (const float*)d_in[4];
    const float* tzeros      = (const float*)d_in[5];
    const int*   tnp         = (const int*)d_in[6];
    const int*   tnz         = (const int*)d_in[7];

    const int B     = in_sizes[6];       // 32768
    const int units = 2 * B;             // (row, part) units; one wave each, 4 per block

    float* partials = (float*)d_ws;      // units * 4 bytes (256 KiB) of scratch

    const int blocks = (units + 3) / 4;
    vltf_kernel<<<blocks, 256, 0, stream>>>(pole_logits, zero_logits,
                                            poles_all, zeros_all,
                                            tpoles, tzeros, tnp, tnz,
                                            partials, units);
    vltf_finalize<<<1, 1024, 0, stream>>>((const float4*)partials, units / 4,
                                          1.0f / (float)B, (float*)d_out);
}

// Round 2
// 111.965 us; speedup vs baseline: 1.1681x; 1.1681x over previous
//
#include <hip/hip_runtime.h>
#include <float.h>

#define NCNT 33   // count classes 0..32
#define NPTS 32   // max poles/zeros

typedef float f32x2 __attribute__((ext_vector_type(2)));

__device__ __forceinline__ f32x2 mk2(float a, float b) { f32x2 r; r.x = a; r.y = b; return r; }

// ---------- DPP helpers ----------
template<int CTRL, bool BC>
__device__ __forceinline__ int dpp_i(int old, int v) {
    return __builtin_amdgcn_update_dpp(old, v, CTRL, 0xF, 0xF, BC);
}

// full-wave (64) sum; result broadcast to all lanes via readlane 63
__device__ __forceinline__ float wave_sum63(float v) {
    v += __int_as_float(dpp_i<0x111, true>(0, __float_as_int(v))); // row_shr:1
    v += __int_as_float(dpp_i<0x112, true>(0, __float_as_int(v))); // row_shr:2
    v += __int_as_float(dpp_i<0x114, true>(0, __float_as_int(v))); // row_shr:4
    v += __int_as_float(dpp_i<0x118, true>(0, __float_as_int(v))); // row_shr:8
    v += __int_as_float(dpp_i<0x142, true>(0, __float_as_int(v))); // row_bcast:15
    v += __int_as_float(dpp_i<0x143, true>(0, __float_as_int(v))); // row_bcast:31
    return __int_as_float(__builtin_amdgcn_readlane(__float_as_int(v), 63));
}

// full-wave max; result broadcast (uniform). bound_ctrl=false + old=v so
// out-of-range source lanes contribute fmax(v,v)=v.
__device__ __forceinline__ float wave_max63(float v) {
#define MX_STEP(C)                                                                    \
    {                                                                                 \
        int o = dpp_i<C, false>(__float_as_int(v), __float_as_int(v));                \
        v = fmaxf(v, __int_as_float(o));                                              \
    }
    MX_STEP(0x111) MX_STEP(0x112) MX_STEP(0x114) MX_STEP(0x118) MX_STEP(0x142) MX_STEP(0x143)
#undef MX_STEP
    return __int_as_float(__builtin_amdgcn_readlane(__float_as_int(v), 63));
}

// ---------- main kernel: 4 single-wave units per 256-thread block ----------
// Per-wave LDS slice (floats): tgt UV [0..63], tgt S [64..95], pred UV [96..159],
// pred S [160..191]. UV layout: float4 j = (u_{2j}, u_{2j+1}, v_{2j}, v_{2j+1});
// u=-2x, v=-2y, s=|pt|^2 (1e30 if invalid). Chamfer reads are wave-uniform
// (broadcast) ds_read_b128 -> no bank conflicts, minimal VALU (pk_fma + min3).
__global__ __launch_bounds__(256) void vltf_kernel(
    const float* __restrict__ pole_logits, const float* __restrict__ zero_logits,
    const float* __restrict__ poles_all,   const float* __restrict__ zeros_all,
    const float* __restrict__ tpoles,      const float* __restrict__ tzeros,
    const int* __restrict__ tnum_p,        const int* __restrict__ tnum_z,
    float* __restrict__ partials)
{
    __shared__ __align__(16) float lds[4 * 192];

    const int lane = threadIdx.x & 63;          // 0..63 within wave
    const int wid  = threadIdx.x >> 6;          // wave 0..3
    const int unit = (blockIdx.x << 2) | wid;   // units = 2*B, divisible by 4
    const int row  = unit >> 1;
    const int part = unit & 1;
    float* myl = lds + wid * 192;               // private per-wave slice

    const float* logits = part ? zero_logits : pole_logits;
    const float* predp  = part ? zeros_all   : poles_all;
    const float* tgtp   = part ? tzeros      : tpoles;
    const int*   tnum   = part ? tnum_z      : tnum_p;

    // ---- cross-entropy + argmax over 33 logits (lanes 0..32 active) ----
    float x = (lane < NCNT) ? logits[row * NCNT + lane] : -FLT_MAX;
    float vmax = wave_max63(x);
    unsigned long long bm = __ballot(lane < NCNT && x == vmax);
    const int np = (int)__builtin_ctzll(bm);      // first-max index == pred count (uniform)
    float e = (lane < NCNT) ? __expf(x - vmax) : 0.f;
    float sume = wave_sum63(e);
    const int nt = tnum[row];                     // target count (uniform)
    float xt = __int_as_float(__builtin_amdgcn_readlane(__float_as_int(x), nt));
    float nll = vmax + __logf(sume) - xt;

    // ---- load own point; stage (u,v,s) for the other half ----
    const bool isPred = lane < 32;
    const int  idx    = lane & 31;
    const float2* ownArr = (const float2*)(isPred ? predp : tgtp);
    const float2  Pt     = ownArr[row * NPTS + idx];
    const int  nown = isPred ? np : nt;
    const bool vown = idx < nown;
    const float sreal = fmaf(Pt.x, Pt.x, Pt.y * Pt.y);

    const int wbase = isPred ? 96 : 0;
    const int uvpos = wbase + ((idx >> 1) << 2) + (idx & 1);
    myl[uvpos]            = vown ? -2.f * Pt.x : 0.f;
    myl[uvpos + 2]        = vown ? -2.f * Pt.y : 0.f;
    myl[wbase + 64 + idx] = vown ? sreal : 1e30f;
    __syncthreads();   // 4-wave rendezvous between identical-length paths: cheap

    // ---- chamfer: min over 32 "other" points, 4 points/iter via pk_fma ----
    const int rbase = isPred ? 0 : 96;            // pred lanes read tgt staging, vice versa
    const float4* UVo = (const float4*)(myl + rbase);
    const float4* So  = (const float4*)(myl + rbase + 64);
    const f32x2 Pxv = mk2(Pt.x, Pt.x);
    const f32x2 Pyv = mk2(Pt.y, Pt.y);
    float m = FLT_MAX;
#pragma unroll
    for (int i = 0; i < 8; ++i) {
        float4 uv0 = UVo[2 * i], uv1 = UVo[2 * i + 1];
        float4 s4  = So[i];
        f32x2 val0 = Pyv * mk2(uv0.z, uv0.w) + mk2(s4.x, s4.y);
        val0       = Pxv * mk2(uv0.x, uv0.y) + val0;
        f32x2 val1 = Pyv * mk2(uv1.z, uv1.w) + mk2(s4.z, s4.w);
        val1       = Pxv * mk2(uv1.x, uv1.y) + val1;
        m = fminf(m, fminf(val0.x, val0.y));      // v_min3_f32
        m = fminf(m, fminf(val1.x, val1.y));
    }

    // ---- per-lane term with wave-uniform special cases ----
    float T;
    if (np > 0 && nt > 0) {
        // uniform reciprocal (1-ulp rcp; exact for these small integer counts' use)
        float inv_n = __builtin_amdgcn_rcpf((float)nown);
        T = vown ? (m + sreal) * inv_n : 0.f;     // |p|^2 folded in once
    } else if (np == 0 && nt == 0) {
        T = 0.f;
    } else if (np == 0) {                          // out = sum_tgt_sq
        T = (!isPred && vown) ? sreal : 0.f;
    } else {                                       // nt == 0 -> sum_pred_sq
        T = (isPred && vown) ? sreal : 0.f;
    }
    float cham = wave_sum63(T);

    if (lane == 0) partials[unit] = 5.f * nll + cham;
}

// ---------- finalize: sum 65536 partials (as 16384 float4), divide by B ----------
__global__ __launch_bounds__(1024) void vltf_finalize(
    const float4* __restrict__ p4, int n4, float invB, float* __restrict__ out)
{
    float s = 0.f;
    for (int i = threadIdx.x; i < n4; i += 1024) {
        float4 v = p4[i];
        s += (v.x + v.y) + (v.z + v.w);
    }
    s = wave_sum63(s);
    __shared__ float sh[16];
    if ((threadIdx.x & 63) == 0) sh[threadIdx.x >> 6] = s;
    __syncthreads();
    if (threadIdx.x == 0) {
        float t = 0.f;
#pragma unroll
        for (int i = 0; i < 16; ++i) t += sh[i];
        out[0] = t * invB;
    }
}

extern "C" void kernel_launch(void* const* d_in, const int* in_sizes, int n_in,
                              void* d_out, int out_size, void* d_ws, size_t ws_size,
                              hipStream_t stream) {
    const float* pole_logits = (const float*)d_in[0];
    const float* zero_logits = (const float*)d_in[1];
    const float* poles_all   = (const float*)d_in[2];
    const float* zeros_all   = (const float*)d_in[3];
    const float* tpoles      = (const float*)d_in[4];
    const float* tzeros      = (const float*)d_in[5];
    const int*   tnp         = (const int*)d_in[6];
    const int*   tnz         = (const int*)d_in[7];

    const int B     = in_sizes[6];       // 32768
    const int units = 2 * B;             // (row, part) units; one wave each, 4 per block

    float* partials = (float*)d_ws;      // units * 4 bytes (256 KiB) of scratch

    vltf_kernel<<<units / 4, 256, 0, stream>>>(pole_logits, zero_logits,
                                               poles_all, zeros_all,
                                               tpoles, tzeros, tnp, tnz, partials);
    vltf_finalize<<<1, 1024, 0, stream>>>((const float4*)partials, units / 4,
                                          1.0f / (float)B, (float*)d_out);
}